// Round 2
// baseline (309.604 us; speedup 1.0000x reference)
//
#include <hip/hip_runtime.h>

// DBASolver: B=16, N=196608, C=2.
// Pass 1: per-batch reduction of H_eff (21 sym entries) + g_eff (6) -- the
//         Schur term (H_pd * invHdd * H_pd^T) is linear in n, fused in.
// Pass 2: 16x tiny 6x6 Gauss-Jordan solves (diag-dominant SPD, no pivoting).
// Pass 3: per-point delta_depth = invHdd * (g_d - H_pd . dp_unclipped).
//
// R1: pair-processing float4 loads, grid 192x16.  -> 1.26 TB/s, latency-bound.
// R2: per-wave LDS transpose staging. R1's per-thread 96B-stride float4 loads
//     made each wave-instruction touch ~64-96 cache lines (vs 16 coalesced),
//     capping issue rate at ~1 load/247cyc/CU. Now:
//       - each wave owns 64 pairs; r/w/J_d float4 loads are lane==pair, i.e.
//         naturally coalesced straight into registers (no LDS needed);
//       - J_p loaded as 6 lane-consecutive float4 loads, transposed through a
//         padded slot-major LDS tile [6][65]float4 (granule class (s+p)%8 ->
//         conflict-free writes AND reads);
//       - per-wave independence: no __syncthreads, one lgkmcnt(0) between
//         scatter-writes and transpose-reads.
//     LDS 25KB/block -> 6 blocks/CU (24 waves/CU). grid (96,16) = 1536 blocks
//     exactly resident, 4 chunk-iterations per wave.
// R3: identical to R2 (bench infra failed, no counters); added
//     sched_barrier(0) after the lgkmcnt fence as defense-in-depth.

constexpr int NACC = 27;  // 21 upper-triangular H entries + 6 g entries

__device__ __forceinline__ void accum_point(
    const float ja[6], const float jb[6],
    float r0, float r1, float conf, float nlam, float jd0, float jd1,
    float lam, float* __restrict__ A, float* __restrict__ g)
{
    float h[6], gp[6];
#pragma unroll
    for (int i = 0; i < 6; ++i) {
        h[i]  = conf * (ja[i] * jd0 + jb[i] * jd1);   // H_pd[b,n,i]
        gp[i] = conf * (ja[i] * r0 + jb[i] * r1);     // g_p contribution
    }
    const float hdd = conf * (jd0 * jd0 + jd1 * jd1);
    const float inv = 1.0f / fmaxf(hdd + lam + nlam, 1e-4f);
    const float gd  = conf * (jd0 * r0 + jd1 * r1);
    const float gdinv = gd * inv;
    int idx = 0;
#pragma unroll
    for (int i = 0; i < 6; ++i) {
        const float hii = h[i] * inv;
#pragma unroll
        for (int j = i; j < 6; ++j) {
            A[idx] += conf * (ja[i] * ja[j] + jb[i] * jb[j]) - hii * h[j];
            ++idx;
        }
        g[i] += gp[i] - h[i] * gdinv;
    }
}

// LDS tile per wave: slot-major J_p, padded: index = s*65 + p  (p = pair 0..63)
// granule class (16B units mod 8) = (65*s + p) % 8 = (s+p) % 8:
//   - transpose-read (fixed s, p = lane): classes (s+l)%8, 8 lanes/class = min
//   - scatter-write (g = k*64+l -> p=g/6, s=g%6): ~8 lanes/class, ~free
constexpr int LDS_PITCH = 65;
constexpr int LDS_WAVE  = 6 * LDS_PITCH;  // 390 float4 = 6240 B per wave

__device__ __forceinline__ void lds_fence()
{
    asm volatile("s_waitcnt lgkmcnt(0)" ::: "memory");
    __builtin_amdgcn_sched_barrier(0);
}

__global__ __launch_bounds__(256) void dba_reduce(
    const float* __restrict__ r, const float* __restrict__ w,
    const float* __restrict__ J_p, const float* __restrict__ J_d,
    const float* __restrict__ lmbda, float* __restrict__ acc, int N)
{
    __shared__ float4 sJ[4][LDS_WAVE];   // 24,960 B
    const int b = blockIdx.y;
    const float lam = lmbda[b];
    const int lane = threadIdx.x & 63;
    const int wave = threadIdx.x >> 6;
    float4* __restrict__ ldsW = sJ[wave];

    float A[21];
    float g[6];
#pragma unroll
    for (int i = 0; i < 21; ++i) A[i] = 0.f;
#pragma unroll
    for (int i = 0; i < 6; ++i) g[i] = 0.f;

    const size_t basePt = (size_t)b * (size_t)N;   // point index base
    const int P  = N >> 1;                         // pairs per batch
    const int PF = P & ~63;                        // full 64-pair chunks

    // pair-granular float4 views (per pair: r/w/J_d = 1 float4, J_p = 6 float4)
    const float4* __restrict__ r4  = (const float4*)r   + (basePt >> 1);
    const float4* __restrict__ w4  = (const float4*)w   + (basePt >> 1);
    const float4* __restrict__ jd4 = (const float4*)J_d + (basePt >> 1);
    const float4* __restrict__ jp4 = (const float4*)J_p + basePt * 3;

    const int gw = blockIdx.x * 4 + wave;          // wave id within batch
    const int chunkStride = gridDim.x * 4;         // waves per batch

    for (int pr0 = gw << 6; pr0 < PF; pr0 += chunkStride << 6) {
        // coalesced register loads: pair index == lane
        const float4 rv = r4[pr0 + lane];
        const float4 wv = w4[pr0 + lane];
        const float4 jd = jd4[pr0 + lane];

        // coalesced J_p stream -> LDS transpose scatter
        const float4* __restrict__ jpseg = jp4 + (size_t)pr0 * 6;
#pragma unroll
        for (int k = 0; k < 6; ++k) {
            const int gg = (k << 6) + lane;        // global float4 idx in chunk
            const float4 q = jpseg[gg];
            const int p = gg / 6;                  // magic-mul, staging only
            const int s = gg - p * 6;
            ldsW[s * LDS_PITCH + p] = q;
        }
        // all scatter-writes landed before any lane transpose-reads
        lds_fence();

        {   // point A of pair `lane`
            const float4 J0 = ldsW[0 * LDS_PITCH + lane];
            const float4 J1 = ldsW[1 * LDS_PITCH + lane];
            const float4 J2 = ldsW[2 * LDS_PITCH + lane];
            const float ja[6] = {J0.x, J0.y, J0.z, J0.w, J1.x, J1.y};
            const float jb[6] = {J1.z, J1.w, J2.x, J2.y, J2.z, J2.w};
            accum_point(ja, jb, rv.x, rv.y, wv.x, wv.y, jd.x, jd.y, lam, A, g);
        }
        {   // point B of pair `lane`
            const float4 J3 = ldsW[3 * LDS_PITCH + lane];
            const float4 J4 = ldsW[4 * LDS_PITCH + lane];
            const float4 J5 = ldsW[5 * LDS_PITCH + lane];
            const float ja[6] = {J3.x, J3.y, J3.z, J3.w, J4.x, J4.y};
            const float jb[6] = {J4.z, J4.w, J5.x, J5.y, J5.z, J5.w};
            accum_point(ja, jb, rv.z, rv.w, wv.z, wv.w, jd.z, jd.w, lam, A, g);
        }
    }

    // generic tail (dead for N=196608: P % 64 == 0) -- direct strided loads
    for (int pr = PF + (int)(blockIdx.x * blockDim.x + threadIdx.x); pr < P;
         pr += (int)(gridDim.x * blockDim.x)) {
        const size_t pt = basePt + ((size_t)pr << 1);
        const float4 rv = *(const float4*)(r + pt * 2);
        const float4 wv = *(const float4*)(w + pt * 2);
        const float4 jd = *(const float4*)(J_d + pt * 2);
        const float4* jp = (const float4*)(J_p + pt * 12);
        const float4 q0 = jp[0], q1 = jp[1], q2 = jp[2];
        const float4 q3 = jp[3], q4 = jp[4], q5 = jp[5];
        {
            const float ja[6] = {q0.x, q0.y, q0.z, q0.w, q1.x, q1.y};
            const float jb[6] = {q1.z, q1.w, q2.x, q2.y, q2.z, q2.w};
            accum_point(ja, jb, rv.x, rv.y, wv.x, wv.y, jd.x, jd.y, lam, A, g);
        }
        {
            const float ja[6] = {q3.x, q3.y, q3.z, q3.w, q4.x, q4.y};
            const float jb[6] = {q4.z, q4.w, q5.x, q5.y, q5.z, q5.w};
            accum_point(ja, jb, rv.z, rv.w, wv.z, wv.w, jd.z, jd.w, lam, A, g);
        }
    }

    float v[NACC];
#pragma unroll
    for (int i = 0; i < 21; ++i) v[i] = A[i];
#pragma unroll
    for (int i = 0; i < 6; ++i) v[21 + i] = g[i];

    // wave-64 shuffle reduction
#pragma unroll
    for (int off = 32; off > 0; off >>= 1) {
#pragma unroll
        for (int i = 0; i < NACC; ++i) v[i] += __shfl_down(v[i], off, 64);
    }

    __shared__ float sred[4][NACC];
    if (lane == 0) {
#pragma unroll
        for (int i = 0; i < NACC; ++i) sred[wave][i] = v[i];
    }
    __syncthreads();
    if (threadIdx.x < NACC) {
        const float s = sred[0][threadIdx.x] + sred[1][threadIdx.x] +
                        sred[2][threadIdx.x] + sred[3][threadIdx.x];
        atomicAdd(&acc[b * 32 + threadIdx.x], s);
    }
}

__global__ void dba_solve(const float* __restrict__ acc,
                          const float* __restrict__ lmbda,
                          float* __restrict__ pose_out,
                          float* __restrict__ dp_ws, int B)
{
    const int b = blockIdx.x * blockDim.x + threadIdx.x;
    if (b >= B) return;
    float M[6][7];
    const float* a = acc + b * 32;
    int idx = 0;
#pragma unroll
    for (int i = 0; i < 6; ++i) {
#pragma unroll
        for (int j = i; j < 6; ++j) {
            const float t = a[idx++];
            M[i][j] = t;
            M[j][i] = t;
        }
    }
#pragma unroll
    for (int i = 0; i < 6; ++i) M[i][6] = a[21 + i];
    const float lam = lmbda[b];
#pragma unroll
    for (int i = 0; i < 6; ++i) M[i][i] += lam + 0.011f;  // lmbda*I + (0.01+0.001)*I

    // Gauss-Jordan, no pivoting (matrix strongly diagonally dominant SPD)
#pragma unroll
    for (int k = 0; k < 6; ++k) {
        const float piv = 1.0f / M[k][k];
#pragma unroll
        for (int j = 0; j < 7; ++j) M[k][j] *= piv;
#pragma unroll
        for (int i = 0; i < 6; ++i) {
            if (i == k) continue;
            const float f = M[i][k];
#pragma unroll
            for (int j = 0; j < 7; ++j) M[i][j] -= f * M[k][j];
        }
    }
#pragma unroll
    for (int i = 0; i < 6; ++i) {
        const float x = M[i][6];              // solution
        dp_ws[b * 6 + i] = x;                 // UNCLIPPED dp feeds pass 3
        pose_out[b * 6 + i] = fminf(fmaxf(x, -2.0f), 2.0f);
    }
}

__device__ __forceinline__ float depth_point(
    const float ja[6], const float jb[6], const float* __restrict__ dp,
    float r0, float r1, float conf, float nlam, float jd0, float jd1, float lam)
{
    float v = 0.f;
#pragma unroll
    for (int i = 0; i < 6; ++i)
        v += (ja[i] * jd0 + jb[i] * jd1) * dp[i];
    v *= conf;
    const float hdd = conf * (jd0 * jd0 + jd1 * jd1);
    const float inv = 1.0f / fmaxf(hdd + lam + nlam, 1e-4f);
    const float gd  = conf * (jd0 * r0 + jd1 * r1);
    return inv * (gd - v);
}

__global__ __launch_bounds__(256) void dba_depth(
    const float* __restrict__ r, const float* __restrict__ w,
    const float* __restrict__ J_p, const float* __restrict__ J_d,
    const float* __restrict__ lmbda, const float* __restrict__ dp_ws,
    float* __restrict__ depth_out, int N)
{
    __shared__ float4 sJ[4][LDS_WAVE];
    const int b = blockIdx.y;
    const float lam = lmbda[b];
    const int lane = threadIdx.x & 63;
    const int wave = threadIdx.x >> 6;
    float4* __restrict__ ldsW = sJ[wave];

    float dp[6];
#pragma unroll
    for (int i = 0; i < 6; ++i) dp[i] = dp_ws[b * 6 + i];

    const size_t basePt = (size_t)b * (size_t)N;
    const int P  = N >> 1;
    const int PF = P & ~63;

    const float4* __restrict__ r4  = (const float4*)r   + (basePt >> 1);
    const float4* __restrict__ w4  = (const float4*)w   + (basePt >> 1);
    const float4* __restrict__ jd4 = (const float4*)J_d + (basePt >> 1);
    const float4* __restrict__ jp4 = (const float4*)J_p + basePt * 3;
    float2* __restrict__ out2 = (float2*)depth_out + (basePt >> 1);

    const int gw = blockIdx.x * 4 + wave;
    const int chunkStride = gridDim.x * 4;

    for (int pr0 = gw << 6; pr0 < PF; pr0 += chunkStride << 6) {
        const float4 rv = r4[pr0 + lane];
        const float4 wv = w4[pr0 + lane];
        const float4 jd = jd4[pr0 + lane];

        const float4* __restrict__ jpseg = jp4 + (size_t)pr0 * 6;
#pragma unroll
        for (int k = 0; k < 6; ++k) {
            const int gg = (k << 6) + lane;
            const float4 q = jpseg[gg];
            const int p = gg / 6;
            const int s = gg - p * 6;
            ldsW[s * LDS_PITCH + p] = q;
        }
        lds_fence();

        float2 outv;
        {
            const float4 J0 = ldsW[0 * LDS_PITCH + lane];
            const float4 J1 = ldsW[1 * LDS_PITCH + lane];
            const float4 J2 = ldsW[2 * LDS_PITCH + lane];
            const float ja[6] = {J0.x, J0.y, J0.z, J0.w, J1.x, J1.y};
            const float jb[6] = {J1.z, J1.w, J2.x, J2.y, J2.z, J2.w};
            outv.x = depth_point(ja, jb, dp, rv.x, rv.y, wv.x, wv.y, jd.x, jd.y, lam);
        }
        {
            const float4 J3 = ldsW[3 * LDS_PITCH + lane];
            const float4 J4 = ldsW[4 * LDS_PITCH + lane];
            const float4 J5 = ldsW[5 * LDS_PITCH + lane];
            const float ja[6] = {J3.x, J3.y, J3.z, J3.w, J4.x, J4.y};
            const float jb[6] = {J4.z, J4.w, J5.x, J5.y, J5.z, J5.w};
            outv.y = depth_point(ja, jb, dp, rv.z, rv.w, wv.z, wv.w, jd.z, jd.w, lam);
        }
        out2[pr0 + lane] = outv;   // coalesced 8B/lane
    }

    // generic tail (dead for N=196608)
    for (int pr = PF + (int)(blockIdx.x * blockDim.x + threadIdx.x); pr < P;
         pr += (int)(gridDim.x * blockDim.x)) {
        const size_t pt = basePt + ((size_t)pr << 1);
        const float4 rv = *(const float4*)(r + pt * 2);
        const float4 wv = *(const float4*)(w + pt * 2);
        const float4 jd = *(const float4*)(J_d + pt * 2);
        const float4* jp = (const float4*)(J_p + pt * 12);
        const float4 q0 = jp[0], q1 = jp[1], q2 = jp[2];
        const float4 q3 = jp[3], q4 = jp[4], q5 = jp[5];
        float2 outv;
        {
            const float ja[6] = {q0.x, q0.y, q0.z, q0.w, q1.x, q1.y};
            const float jb[6] = {q1.z, q1.w, q2.x, q2.y, q2.z, q2.w};
            outv.x = depth_point(ja, jb, dp, rv.x, rv.y, wv.x, wv.y, jd.x, jd.y, lam);
        }
        {
            const float ja[6] = {q3.x, q3.y, q3.z, q3.w, q4.x, q4.y};
            const float jb[6] = {q4.z, q4.w, q5.x, q5.y, q5.z, q5.w};
            outv.y = depth_point(ja, jb, dp, rv.z, rv.w, wv.z, wv.w, jd.z, jd.w, lam);
        }
        *(float2*)(depth_out + pt) = outv;
    }
}

extern "C" void kernel_launch(void* const* d_in, const int* in_sizes, int n_in,
                              void* d_out, int out_size, void* d_ws, size_t ws_size,
                              hipStream_t stream)
{
    const float* r   = (const float*)d_in[0];
    const float* w   = (const float*)d_in[1];
    const float* J_p = (const float*)d_in[2];
    const float* J_d = (const float*)d_in[3];
    const float* lmb = (const float*)d_in[4];
    const int B = in_sizes[4];            // 16
    const int N = in_sizes[0] / (B * 2);  // 196608

    float* acc   = (float*)d_ws;           // B*32 floats of accumulators
    float* dp_ws = (float*)d_ws + B * 32;  // B*6 floats of unclipped dp
    float* out   = (float*)d_out;

    hipMemsetAsync(acc, 0, B * 32 * sizeof(float), stream);

    // 96x16 = 1536 blocks @ 25KB LDS = 6 blocks/CU exactly resident
    // (24 waves/CU), 4 chunk-iterations of 64 pairs per wave.
    dim3 grid(96, B);
    dba_reduce<<<grid, 256, 0, stream>>>(r, w, J_p, J_d, lmb, acc, N);
    dba_solve<<<1, 64, 0, stream>>>(acc, lmb, out, dp_ws, B);
    dba_depth<<<grid, 256, 0, stream>>>(r, w, J_p, J_d, lmb, dp_ws, out + B * 6, N);
}

// Round 3
// 304.951 us; speedup vs baseline: 1.0153x; 1.0153x over previous
//
#include <hip/hip_runtime.h>

// DBASolver: B=16, N=196608, C=2.
// Pass 1: per-batch reduction of H_eff (21 sym entries) + g_eff (6).
// Pass 2: 16x tiny 6x6 Gauss-Jordan solves.
// Pass 3: per-point delta_depth = invHdd * (g_d - H_pd . dp_unclipped).
//
// R1: pair-processing float4 loads. 92us/pass, 1.25 TB/s, latency-bound.
// R2/R3: per-wave LDS transpose staging (perfect coalescing). NEUTRAL: 92us,
//     identical to R1 -> coalescing is NOT the bottleneck. Delivered rate
//     pins at ~2.46 TB/s with all pipes idle; waves fully queued (23us/iter).
// R4: two independent mechanisms against the supply stall:
//     (a) register prefetch double-buffer: issue chunk t+1's 9 loads before
//         staging/computing chunk t -> LDS writes consume already-arrived
//         registers, no vmcnt wait in compute phase, ~9KB/wave continuously
//         in flight (kills the per-iteration dead window);
//     (b) non-temporal (nt) loads on all big streams + nt store of depth_out:
//         stop LLC/MALL allocation churn (226+226+604 MB streamed through
//         256MB LLC per timed iteration).
//     Also hoisted loop-invariant LDS transpose addresses (6 magic-divs).

using f4 = __attribute__((ext_vector_type(4))) float;
using f2 = __attribute__((ext_vector_type(2))) float;

__device__ __forceinline__ f4 ntload4(const f4* p) {
    return __builtin_nontemporal_load(p);
}

constexpr int NACC = 27;  // 21 upper-triangular H entries + 6 g entries

__device__ __forceinline__ void accum_point(
    const float ja[6], const float jb[6],
    float r0, float r1, float conf, float nlam, float jd0, float jd1,
    float lam, float* __restrict__ A, float* __restrict__ g)
{
    float h[6], gp[6];
#pragma unroll
    for (int i = 0; i < 6; ++i) {
        h[i]  = conf * (ja[i] * jd0 + jb[i] * jd1);   // H_pd[b,n,i]
        gp[i] = conf * (ja[i] * r0 + jb[i] * r1);     // g_p contribution
    }
    const float hdd = conf * (jd0 * jd0 + jd1 * jd1);
    const float inv = 1.0f / fmaxf(hdd + lam + nlam, 1e-4f);
    const float gd  = conf * (jd0 * r0 + jd1 * r1);
    const float gdinv = gd * inv;
    int idx = 0;
#pragma unroll
    for (int i = 0; i < 6; ++i) {
        const float hii = h[i] * inv;
#pragma unroll
        for (int j = i; j < 6; ++j) {
            A[idx] += conf * (ja[i] * ja[j] + jb[i] * jb[j]) - hii * h[j];
            ++idx;
        }
        g[i] += gp[i] - h[i] * gdinv;
    }
}

// LDS tile per wave: slot-major J_p, padded: index = s*65 + p  (p = pair 0..63)
// granule class (16B units mod 8) = (s+p)%8 -> conflict-free read & scatter.
constexpr int LDS_PITCH = 65;
constexpr int LDS_WAVE  = 6 * LDS_PITCH;  // 390 f4 = 6240 B per wave

__device__ __forceinline__ void lds_fence()
{
    asm volatile("s_waitcnt lgkmcnt(0)" ::: "memory");
    __builtin_amdgcn_sched_barrier(0);
}

__global__ __launch_bounds__(256) void dba_reduce(
    const float* __restrict__ r, const float* __restrict__ w,
    const float* __restrict__ J_p, const float* __restrict__ J_d,
    const float* __restrict__ lmbda, float* __restrict__ acc, int N)
{
    __shared__ f4 sJ[4][LDS_WAVE];   // 24,960 B
    const int b = blockIdx.y;
    const float lam = lmbda[b];
    const int lane = threadIdx.x & 63;
    const int wave = threadIdx.x >> 6;
    f4* __restrict__ ldsW = sJ[wave];

    float A[21];
    float g[6];
#pragma unroll
    for (int i = 0; i < 21; ++i) A[i] = 0.f;
#pragma unroll
    for (int i = 0; i < 6; ++i) g[i] = 0.f;

    const size_t basePt = (size_t)b * (size_t)N;
    const int P  = N >> 1;
    const int PF = P & ~63;

    const f4* __restrict__ r4  = (const f4*)r   + (basePt >> 1);
    const f4* __restrict__ w4  = (const f4*)w   + (basePt >> 1);
    const f4* __restrict__ jd4 = (const f4*)J_d + (basePt >> 1);
    const f4* __restrict__ jp4 = (const f4*)J_p + basePt * 3;

    const int gw = blockIdx.x * 4 + wave;
    const int step = (gridDim.x * 4) << 6;

    // loop-invariant LDS transpose-scatter addresses (gg = k*64+lane -> p,s)
    f4* wadr[6];
#pragma unroll
    for (int k = 0; k < 6; ++k) {
        const int gg = (k << 6) + lane;
        const int p = gg / 6;
        const int s = gg - p * 6;
        wadr[k] = &ldsW[s * LDS_PITCH + p];
    }
    const f4* radr0 = &ldsW[0 * LDS_PITCH + lane];
    const f4* radr1 = &ldsW[1 * LDS_PITCH + lane];
    const f4* radr2 = &ldsW[2 * LDS_PITCH + lane];
    const f4* radr3 = &ldsW[3 * LDS_PITCH + lane];
    const f4* radr4 = &ldsW[4 * LDS_PITCH + lane];
    const f4* radr5 = &ldsW[5 * LDS_PITCH + lane];

    int pr0 = gw << 6;
    if (pr0 < PF) {
        // prologue: load chunk 0 into current registers (nt streams)
        const f4* jps = jp4 + (size_t)pr0 * 6;
        f4 c_rv = ntload4(r4 + pr0 + lane);
        f4 c_wv = ntload4(w4 + pr0 + lane);
        f4 c_jd = ntload4(jd4 + pr0 + lane);
        f4 c_q0 = ntload4(jps + 0 * 64 + lane);
        f4 c_q1 = ntload4(jps + 1 * 64 + lane);
        f4 c_q2 = ntload4(jps + 2 * 64 + lane);
        f4 c_q3 = ntload4(jps + 3 * 64 + lane);
        f4 c_q4 = ntload4(jps + 4 * 64 + lane);
        f4 c_q5 = ntload4(jps + 5 * 64 + lane);

        for (; pr0 < PF; pr0 += step) {
            // issue next chunk's loads FIRST (address-clamped on last iter)
            const int nxt = (pr0 + step < PF) ? (pr0 + step) : pr0;
            const f4* jpn = jp4 + (size_t)nxt * 6;
            f4 n_rv = ntload4(r4 + nxt + lane);
            f4 n_wv = ntload4(w4 + nxt + lane);
            f4 n_jd = ntload4(jd4 + nxt + lane);
            f4 n_q0 = ntload4(jpn + 0 * 64 + lane);
            f4 n_q1 = ntload4(jpn + 1 * 64 + lane);
            f4 n_q2 = ntload4(jpn + 2 * 64 + lane);
            f4 n_q3 = ntload4(jpn + 3 * 64 + lane);
            f4 n_q4 = ntload4(jpn + 4 * 64 + lane);
            f4 n_q5 = ntload4(jpn + 5 * 64 + lane);

            // stage CURRENT J_p (registers already resident -> no vmcnt wait)
            *wadr[0] = c_q0;
            *wadr[1] = c_q1;
            *wadr[2] = c_q2;
            *wadr[3] = c_q3;
            *wadr[4] = c_q4;
            *wadr[5] = c_q5;
            lds_fence();

            {   // point A of pair `lane`
                const f4 J0 = *radr0;
                const f4 J1 = *radr1;
                const f4 J2 = *radr2;
                const float ja[6] = {J0[0], J0[1], J0[2], J0[3], J1[0], J1[1]};
                const float jb[6] = {J1[2], J1[3], J2[0], J2[1], J2[2], J2[3]};
                accum_point(ja, jb, c_rv[0], c_rv[1], c_wv[0], c_wv[1],
                            c_jd[0], c_jd[1], lam, A, g);
            }
            {   // point B of pair `lane`
                const f4 J3 = *radr3;
                const f4 J4 = *radr4;
                const f4 J5 = *radr5;
                const float ja[6] = {J3[0], J3[1], J3[2], J3[3], J4[0], J4[1]};
                const float jb[6] = {J4[2], J4[3], J5[0], J5[1], J5[2], J5[3]};
                accum_point(ja, jb, c_rv[2], c_rv[3], c_wv[2], c_wv[3],
                            c_jd[2], c_jd[3], lam, A, g);
            }

            // rotate prefetched registers in
            c_rv = n_rv; c_wv = n_wv; c_jd = n_jd;
            c_q0 = n_q0; c_q1 = n_q1; c_q2 = n_q2;
            c_q3 = n_q3; c_q4 = n_q4; c_q5 = n_q5;
        }
    }

    // generic tail (dead for N=196608: P % 64 == 0)
    for (int pr = PF + (int)(blockIdx.x * blockDim.x + threadIdx.x); pr < P;
         pr += (int)(gridDim.x * blockDim.x)) {
        const size_t pt = basePt + ((size_t)pr << 1);
        const float4 rv = *(const float4*)(r + pt * 2);
        const float4 wv = *(const float4*)(w + pt * 2);
        const float4 jd = *(const float4*)(J_d + pt * 2);
        const float4* jp = (const float4*)(J_p + pt * 12);
        const float4 q0 = jp[0], q1 = jp[1], q2 = jp[2];
        const float4 q3 = jp[3], q4 = jp[4], q5 = jp[5];
        {
            const float ja[6] = {q0.x, q0.y, q0.z, q0.w, q1.x, q1.y};
            const float jb[6] = {q1.z, q1.w, q2.x, q2.y, q2.z, q2.w};
            accum_point(ja, jb, rv.x, rv.y, wv.x, wv.y, jd.x, jd.y, lam, A, g);
        }
        {
            const float ja[6] = {q3.x, q3.y, q3.z, q3.w, q4.x, q4.y};
            const float jb[6] = {q4.z, q4.w, q5.x, q5.y, q5.z, q5.w};
            accum_point(ja, jb, rv.z, rv.w, wv.z, wv.w, jd.z, jd.w, lam, A, g);
        }
    }

    float v[NACC];
#pragma unroll
    for (int i = 0; i < 21; ++i) v[i] = A[i];
#pragma unroll
    for (int i = 0; i < 6; ++i) v[21 + i] = g[i];

#pragma unroll
    for (int off = 32; off > 0; off >>= 1) {
#pragma unroll
        for (int i = 0; i < NACC; ++i) v[i] += __shfl_down(v[i], off, 64);
    }

    __shared__ float sred[4][NACC];
    if (lane == 0) {
#pragma unroll
        for (int i = 0; i < NACC; ++i) sred[wave][i] = v[i];
    }
    __syncthreads();
    if (threadIdx.x < NACC) {
        const float s = sred[0][threadIdx.x] + sred[1][threadIdx.x] +
                        sred[2][threadIdx.x] + sred[3][threadIdx.x];
        atomicAdd(&acc[b * 32 + threadIdx.x], s);
    }
}

__global__ void dba_solve(const float* __restrict__ acc,
                          const float* __restrict__ lmbda,
                          float* __restrict__ pose_out,
                          float* __restrict__ dp_ws, int B)
{
    const int b = blockIdx.x * blockDim.x + threadIdx.x;
    if (b >= B) return;
    float M[6][7];
    const float* a = acc + b * 32;
    int idx = 0;
#pragma unroll
    for (int i = 0; i < 6; ++i) {
#pragma unroll
        for (int j = i; j < 6; ++j) {
            const float t = a[idx++];
            M[i][j] = t;
            M[j][i] = t;
        }
    }
#pragma unroll
    for (int i = 0; i < 6; ++i) M[i][6] = a[21 + i];
    const float lam = lmbda[b];
#pragma unroll
    for (int i = 0; i < 6; ++i) M[i][i] += lam + 0.011f;

#pragma unroll
    for (int k = 0; k < 6; ++k) {
        const float piv = 1.0f / M[k][k];
#pragma unroll
        for (int j = 0; j < 7; ++j) M[k][j] *= piv;
#pragma unroll
        for (int i = 0; i < 6; ++i) {
            if (i == k) continue;
            const float f = M[i][k];
#pragma unroll
            for (int j = 0; j < 7; ++j) M[i][j] -= f * M[k][j];
        }
    }
#pragma unroll
    for (int i = 0; i < 6; ++i) {
        const float x = M[i][6];
        dp_ws[b * 6 + i] = x;                 // UNCLIPPED dp feeds pass 3
        pose_out[b * 6 + i] = fminf(fmaxf(x, -2.0f), 2.0f);
    }
}

__device__ __forceinline__ float depth_point(
    const float ja[6], const float jb[6], const float* __restrict__ dp,
    float r0, float r1, float conf, float nlam, float jd0, float jd1, float lam)
{
    float v = 0.f;
#pragma unroll
    for (int i = 0; i < 6; ++i)
        v += (ja[i] * jd0 + jb[i] * jd1) * dp[i];
    v *= conf;
    const float hdd = conf * (jd0 * jd0 + jd1 * jd1);
    const float inv = 1.0f / fmaxf(hdd + lam + nlam, 1e-4f);
    const float gd  = conf * (jd0 * r0 + jd1 * r1);
    return inv * (gd - v);
}

__global__ __launch_bounds__(256) void dba_depth(
    const float* __restrict__ r, const float* __restrict__ w,
    const float* __restrict__ J_p, const float* __restrict__ J_d,
    const float* __restrict__ lmbda, const float* __restrict__ dp_ws,
    float* __restrict__ depth_out, int N)
{
    __shared__ f4 sJ[4][LDS_WAVE];
    const int b = blockIdx.y;
    const float lam = lmbda[b];
    const int lane = threadIdx.x & 63;
    const int wave = threadIdx.x >> 6;
    f4* __restrict__ ldsW = sJ[wave];

    float dp[6];
#pragma unroll
    for (int i = 0; i < 6; ++i) dp[i] = dp_ws[b * 6 + i];

    const size_t basePt = (size_t)b * (size_t)N;
    const int P  = N >> 1;
    const int PF = P & ~63;

    const f4* __restrict__ r4  = (const f4*)r   + (basePt >> 1);
    const f4* __restrict__ w4  = (const f4*)w   + (basePt >> 1);
    const f4* __restrict__ jd4 = (const f4*)J_d + (basePt >> 1);
    const f4* __restrict__ jp4 = (const f4*)J_p + basePt * 3;
    f2* __restrict__ out2 = (f2*)depth_out + (basePt >> 1);

    const int gw = blockIdx.x * 4 + wave;
    const int step = (gridDim.x * 4) << 6;

    f4* wadr[6];
#pragma unroll
    for (int k = 0; k < 6; ++k) {
        const int gg = (k << 6) + lane;
        const int p = gg / 6;
        const int s = gg - p * 6;
        wadr[k] = &ldsW[s * LDS_PITCH + p];
    }
    const f4* radr0 = &ldsW[0 * LDS_PITCH + lane];
    const f4* radr1 = &ldsW[1 * LDS_PITCH + lane];
    const f4* radr2 = &ldsW[2 * LDS_PITCH + lane];
    const f4* radr3 = &ldsW[3 * LDS_PITCH + lane];
    const f4* radr4 = &ldsW[4 * LDS_PITCH + lane];
    const f4* radr5 = &ldsW[5 * LDS_PITCH + lane];

    int pr0 = gw << 6;
    if (pr0 < PF) {
        const f4* jps = jp4 + (size_t)pr0 * 6;
        f4 c_rv = ntload4(r4 + pr0 + lane);
        f4 c_wv = ntload4(w4 + pr0 + lane);
        f4 c_jd = ntload4(jd4 + pr0 + lane);
        f4 c_q0 = ntload4(jps + 0 * 64 + lane);
        f4 c_q1 = ntload4(jps + 1 * 64 + lane);
        f4 c_q2 = ntload4(jps + 2 * 64 + lane);
        f4 c_q3 = ntload4(jps + 3 * 64 + lane);
        f4 c_q4 = ntload4(jps + 4 * 64 + lane);
        f4 c_q5 = ntload4(jps + 5 * 64 + lane);

        for (; pr0 < PF; pr0 += step) {
            const int nxt = (pr0 + step < PF) ? (pr0 + step) : pr0;
            const f4* jpn = jp4 + (size_t)nxt * 6;
            f4 n_rv = ntload4(r4 + nxt + lane);
            f4 n_wv = ntload4(w4 + nxt + lane);
            f4 n_jd = ntload4(jd4 + nxt + lane);
            f4 n_q0 = ntload4(jpn + 0 * 64 + lane);
            f4 n_q1 = ntload4(jpn + 1 * 64 + lane);
            f4 n_q2 = ntload4(jpn + 2 * 64 + lane);
            f4 n_q3 = ntload4(jpn + 3 * 64 + lane);
            f4 n_q4 = ntload4(jpn + 4 * 64 + lane);
            f4 n_q5 = ntload4(jpn + 5 * 64 + lane);

            *wadr[0] = c_q0;
            *wadr[1] = c_q1;
            *wadr[2] = c_q2;
            *wadr[3] = c_q3;
            *wadr[4] = c_q4;
            *wadr[5] = c_q5;
            lds_fence();

            f2 outv;
            {
                const f4 J0 = *radr0;
                const f4 J1 = *radr1;
                const f4 J2 = *radr2;
                const float ja[6] = {J0[0], J0[1], J0[2], J0[3], J1[0], J1[1]};
                const float jb[6] = {J1[2], J1[3], J2[0], J2[1], J2[2], J2[3]};
                outv[0] = depth_point(ja, jb, dp, c_rv[0], c_rv[1], c_wv[0],
                                      c_wv[1], c_jd[0], c_jd[1], lam);
            }
            {
                const f4 J3 = *radr3;
                const f4 J4 = *radr4;
                const f4 J5 = *radr5;
                const float ja[6] = {J3[0], J3[1], J3[2], J3[3], J4[0], J4[1]};
                const float jb[6] = {J4[2], J4[3], J5[0], J5[1], J5[2], J5[3]};
                outv[1] = depth_point(ja, jb, dp, c_rv[2], c_rv[3], c_wv[2],
                                      c_wv[3], c_jd[2], c_jd[3], lam);
            }
            __builtin_nontemporal_store(outv, out2 + pr0 + lane);

            c_rv = n_rv; c_wv = n_wv; c_jd = n_jd;
            c_q0 = n_q0; c_q1 = n_q1; c_q2 = n_q2;
            c_q3 = n_q3; c_q4 = n_q4; c_q5 = n_q5;
        }
    }

    // generic tail (dead for N=196608)
    for (int pr = PF + (int)(blockIdx.x * blockDim.x + threadIdx.x); pr < P;
         pr += (int)(gridDim.x * blockDim.x)) {
        const size_t pt = basePt + ((size_t)pr << 1);
        const float4 rv = *(const float4*)(r + pt * 2);
        const float4 wv = *(const float4*)(w + pt * 2);
        const float4 jd = *(const float4*)(J_d + pt * 2);
        const float4* jp = (const float4*)(J_p + pt * 12);
        const float4 q0 = jp[0], q1 = jp[1], q2 = jp[2];
        const float4 q3 = jp[3], q4 = jp[4], q5 = jp[5];
        float2 outv;
        {
            const float ja[6] = {q0.x, q0.y, q0.z, q0.w, q1.x, q1.y};
            const float jb[6] = {q1.z, q1.w, q2.x, q2.y, q2.z, q2.w};
            outv.x = depth_point(ja, jb, dp, rv.x, rv.y, wv.x, wv.y, jd.x, jd.y, lam);
        }
        {
            const float ja[6] = {q3.x, q3.y, q3.z, q3.w, q4.x, q4.y};
            const float jb[6] = {q4.z, q4.w, q5.x, q5.y, q5.z, q5.w};
            outv.y = depth_point(ja, jb, dp, rv.z, rv.w, wv.z, wv.w, jd.z, jd.w, lam);
        }
        *(float2*)(depth_out + pt) = outv;
    }
}

extern "C" void kernel_launch(void* const* d_in, const int* in_sizes, int n_in,
                              void* d_out, int out_size, void* d_ws, size_t ws_size,
                              hipStream_t stream)
{
    const float* r   = (const float*)d_in[0];
    const float* w   = (const float*)d_in[1];
    const float* J_p = (const float*)d_in[2];
    const float* J_d = (const float*)d_in[3];
    const float* lmb = (const float*)d_in[4];
    const int B = in_sizes[4];            // 16
    const int N = in_sizes[0] / (B * 2);  // 196608

    float* acc   = (float*)d_ws;           // B*32 floats of accumulators
    float* dp_ws = (float*)d_ws + B * 32;  // B*6 floats of unclipped dp
    float* out   = (float*)d_out;

    hipMemsetAsync(acc, 0, B * 32 * sizeof(float), stream);

    dim3 grid(96, B);
    dba_reduce<<<grid, 256, 0, stream>>>(r, w, J_p, J_d, lmb, acc, N);
    dba_solve<<<1, 64, 0, stream>>>(acc, lmb, out, dp_ws, B);
    dba_depth<<<grid, 256, 0, stream>>>(r, w, J_p, J_d, lmb, dp_ws, out + B * 6, N);
}

// Round 5
// 299.308 us; speedup vs baseline: 1.0344x; 1.0189x over previous
//
#include <hip/hip_runtime.h>

// DBASolver: B=16, N=196608, C=2.
// Pass 1: per-batch reduction of H_eff (21 sym) + g_eff (6); also streams
//         per-point depth coefficients (hii[6], gdinv) to a workspace cache.
// Pass 2: 16x tiny 6x6 Gauss-Jordan solves.
// Pass 3: delta_depth[n] = gdinv[n] - hii[n].dp  -- reads 32B/pt cache
//         instead of re-reading 72B/pt of raw inputs.
//
// History: R1 strided float4 (92us/pass, 2.5 TB/s delivered). R2 coalesced
// LDS transpose: NEUTRAL. R4 reg-prefetch + nt: ~neutral (-5us/pass).
// Model: per-CU read throughput caps at ~4 B/cyc (L1 line-fill queue x 64B /
// ~550cyc latency); copy ubench sits at same cap; writes are uncapped
// (fill: 6.9 TB/s @ 10% occ). Only lever: READ FEWER BYTES.
// R5: pass3 re-read (226.5 MB) -> 100.7 MB cached coefficients (computed for
// free in pass1), written through LLC so pass3 mostly hits LLC.
// Fallback to full-recompute pass3 if ws_size too small.
// R6: resubmit of R5 (bench infra failed twice, no verdict; code re-audited:
// workspace guard, record indexing, no capture violations).

using f4 = __attribute__((ext_vector_type(4))) float;
using f2 = __attribute__((ext_vector_type(2))) float;

__device__ __forceinline__ f4 ntload4(const f4* p) {
    return __builtin_nontemporal_load(p);
}

constexpr int NACC = 27;  // 21 upper-triangular H entries + 6 g entries

// Computes the per-point contribution AND exports c7 = {hii[0..5], gdinv}
// (exact values pass 3 needs: depth = gdinv - hii.dp). Zero extra math.
__device__ __forceinline__ void accum_point(
    const float ja[6], const float jb[6],
    float r0, float r1, float conf, float nlam, float jd0, float jd1,
    float lam, float* __restrict__ A, float* __restrict__ g,
    float* __restrict__ c7)
{
    float h[6], gp[6];
#pragma unroll
    for (int i = 0; i < 6; ++i) {
        h[i]  = conf * (ja[i] * jd0 + jb[i] * jd1);   // H_pd[b,n,i]
        gp[i] = conf * (ja[i] * r0 + jb[i] * r1);     // g_p contribution
    }
    const float hdd = conf * (jd0 * jd0 + jd1 * jd1);
    const float inv = 1.0f / fmaxf(hdd + lam + nlam, 1e-4f);
    const float gd  = conf * (jd0 * r0 + jd1 * r1);
    const float gdinv = gd * inv;
    c7[6] = gdinv;
    int idx = 0;
#pragma unroll
    for (int i = 0; i < 6; ++i) {
        const float hii = h[i] * inv;
        c7[i] = hii;
#pragma unroll
        for (int j = i; j < 6; ++j) {
            A[idx] += conf * (ja[i] * ja[j] + jb[i] * jb[j]) - hii * h[j];
            ++idx;
        }
        g[i] += gp[i] - h[i] * gdinv;
    }
}

// LDS tile per wave: slot-major J_p, padded: index = s*65 + p  (p = pair 0..63)
// granule class (16B units mod 8) = (s+p)%8 -> conflict-free read & scatter.
constexpr int LDS_PITCH = 65;
constexpr int LDS_WAVE  = 6 * LDS_PITCH;  // 390 f4 = 6240 B per wave

__device__ __forceinline__ void lds_fence()
{
    asm volatile("s_waitcnt lgkmcnt(0)" ::: "memory");
    __builtin_amdgcn_sched_barrier(0);
}

__device__ __forceinline__ void store_rec(f4* __restrict__ rec, const float* c7)
{
    f4 lo = {c7[0], c7[1], c7[2], c7[3]};
    f4 hi = {c7[4], c7[5], c7[6], 0.f};
    rec[0] = lo;
    rec[1] = hi;
}

__global__ __launch_bounds__(256) void dba_reduce(
    const float* __restrict__ r, const float* __restrict__ w,
    const float* __restrict__ J_p, const float* __restrict__ J_d,
    const float* __restrict__ lmbda, float* __restrict__ acc,
    float* __restrict__ cache, int do_cache, int N)
{
    __shared__ f4 sJ[4][LDS_WAVE];   // 24,960 B
    const int b = blockIdx.y;
    const float lam = lmbda[b];
    const int lane = threadIdx.x & 63;
    const int wave = threadIdx.x >> 6;
    f4* __restrict__ ldsW = sJ[wave];

    float A[21];
    float g[6];
#pragma unroll
    for (int i = 0; i < 21; ++i) A[i] = 0.f;
#pragma unroll
    for (int i = 0; i < 6; ++i) g[i] = 0.f;

    const size_t basePt = (size_t)b * (size_t)N;
    const int P  = N >> 1;
    const int PF = P & ~63;

    const f4* __restrict__ r4  = (const f4*)r   + (basePt >> 1);
    const f4* __restrict__ w4  = (const f4*)w   + (basePt >> 1);
    const f4* __restrict__ jd4 = (const f4*)J_d + (basePt >> 1);
    const f4* __restrict__ jp4 = (const f4*)J_p + basePt * 3;
    f4* __restrict__ cb = (f4*)cache + basePt * 2;  // 2 f4 per point

    const int gw = blockIdx.x * 4 + wave;
    const int step = (gridDim.x * 4) << 6;

    // loop-invariant LDS transpose-scatter addresses (gg = k*64+lane -> p,s)
    f4* wadr[6];
#pragma unroll
    for (int k = 0; k < 6; ++k) {
        const int gg = (k << 6) + lane;
        const int p = gg / 6;
        const int s = gg - p * 6;
        wadr[k] = &ldsW[s * LDS_PITCH + p];
    }
    const f4* radr0 = &ldsW[0 * LDS_PITCH + lane];
    const f4* radr1 = &ldsW[1 * LDS_PITCH + lane];
    const f4* radr2 = &ldsW[2 * LDS_PITCH + lane];
    const f4* radr3 = &ldsW[3 * LDS_PITCH + lane];
    const f4* radr4 = &ldsW[4 * LDS_PITCH + lane];
    const f4* radr5 = &ldsW[5 * LDS_PITCH + lane];

    int pr0 = gw << 6;
    if (pr0 < PF) {
        // prologue: load chunk 0 into current registers (nt streams)
        const f4* jps = jp4 + (size_t)pr0 * 6;
        f4 c_rv = ntload4(r4 + pr0 + lane);
        f4 c_wv = ntload4(w4 + pr0 + lane);
        f4 c_jd = ntload4(jd4 + pr0 + lane);
        f4 c_q0 = ntload4(jps + 0 * 64 + lane);
        f4 c_q1 = ntload4(jps + 1 * 64 + lane);
        f4 c_q2 = ntload4(jps + 2 * 64 + lane);
        f4 c_q3 = ntload4(jps + 3 * 64 + lane);
        f4 c_q4 = ntload4(jps + 4 * 64 + lane);
        f4 c_q5 = ntload4(jps + 5 * 64 + lane);

        for (; pr0 < PF; pr0 += step) {
            // issue next chunk's loads FIRST (address-clamped on last iter)
            const int nxt = (pr0 + step < PF) ? (pr0 + step) : pr0;
            const f4* jpn = jp4 + (size_t)nxt * 6;
            f4 n_rv = ntload4(r4 + nxt + lane);
            f4 n_wv = ntload4(w4 + nxt + lane);
            f4 n_jd = ntload4(jd4 + nxt + lane);
            f4 n_q0 = ntload4(jpn + 0 * 64 + lane);
            f4 n_q1 = ntload4(jpn + 1 * 64 + lane);
            f4 n_q2 = ntload4(jpn + 2 * 64 + lane);
            f4 n_q3 = ntload4(jpn + 3 * 64 + lane);
            f4 n_q4 = ntload4(jpn + 4 * 64 + lane);
            f4 n_q5 = ntload4(jpn + 5 * 64 + lane);

            // stage CURRENT J_p (registers already resident -> no vmcnt wait)
            *wadr[0] = c_q0;
            *wadr[1] = c_q1;
            *wadr[2] = c_q2;
            *wadr[3] = c_q3;
            *wadr[4] = c_q4;
            *wadr[5] = c_q5;
            lds_fence();

            float c7a[7], c7b[7];
            {   // point A of pair `lane`
                const f4 J0 = *radr0;
                const f4 J1 = *radr1;
                const f4 J2 = *radr2;
                const float ja[6] = {J0[0], J0[1], J0[2], J0[3], J1[0], J1[1]};
                const float jb[6] = {J1[2], J1[3], J2[0], J2[1], J2[2], J2[3]};
                accum_point(ja, jb, c_rv[0], c_rv[1], c_wv[0], c_wv[1],
                            c_jd[0], c_jd[1], lam, A, g, c7a);
            }
            {   // point B of pair `lane`
                const f4 J3 = *radr3;
                const f4 J4 = *radr4;
                const f4 J5 = *radr5;
                const float ja[6] = {J3[0], J3[1], J3[2], J3[3], J4[0], J4[1]};
                const float jb[6] = {J4[2], J4[3], J5[0], J5[1], J5[2], J5[3]};
                accum_point(ja, jb, c_rv[2], c_rv[3], c_wv[2], c_wv[3],
                            c_jd[2], c_jd[3], lam, A, g, c7b);
            }
            if (do_cache) {
                f4* rec = cb + (size_t)(pr0 + lane) * 4;  // pair -> 4 f4
                store_rec(rec + 0, c7a);
                store_rec(rec + 2, c7b);
            }

            // rotate prefetched registers in
            c_rv = n_rv; c_wv = n_wv; c_jd = n_jd;
            c_q0 = n_q0; c_q1 = n_q1; c_q2 = n_q2;
            c_q3 = n_q3; c_q4 = n_q4; c_q5 = n_q5;
        }
    }

    // generic tail (dead for N=196608: P % 64 == 0)
    for (int pr = PF + (int)(blockIdx.x * blockDim.x + threadIdx.x); pr < P;
         pr += (int)(gridDim.x * blockDim.x)) {
        const size_t pt = basePt + ((size_t)pr << 1);
        const float4 rv = *(const float4*)(r + pt * 2);
        const float4 wv = *(const float4*)(w + pt * 2);
        const float4 jd = *(const float4*)(J_d + pt * 2);
        const float4* jp = (const float4*)(J_p + pt * 12);
        const float4 q0 = jp[0], q1 = jp[1], q2 = jp[2];
        const float4 q3 = jp[3], q4 = jp[4], q5 = jp[5];
        float c7a[7], c7b[7];
        {
            const float ja[6] = {q0.x, q0.y, q0.z, q0.w, q1.x, q1.y};
            const float jb[6] = {q1.z, q1.w, q2.x, q2.y, q2.z, q2.w};
            accum_point(ja, jb, rv.x, rv.y, wv.x, wv.y, jd.x, jd.y, lam, A, g, c7a);
        }
        {
            const float ja[6] = {q3.x, q3.y, q3.z, q3.w, q4.x, q4.y};
            const float jb[6] = {q4.z, q4.w, q5.x, q5.y, q5.z, q5.w};
            accum_point(ja, jb, rv.z, rv.w, wv.z, wv.w, jd.z, jd.w, lam, A, g, c7b);
        }
        if (do_cache) {
            f4* rec = cb + (size_t)pr * 4;
            store_rec(rec + 0, c7a);
            store_rec(rec + 2, c7b);
        }
    }

    float v[NACC];
#pragma unroll
    for (int i = 0; i < 21; ++i) v[i] = A[i];
#pragma unroll
    for (int i = 0; i < 6; ++i) v[21 + i] = g[i];

#pragma unroll
    for (int off = 32; off > 0; off >>= 1) {
#pragma unroll
        for (int i = 0; i < NACC; ++i) v[i] += __shfl_down(v[i], off, 64);
    }

    __shared__ float sred[4][NACC];
    if (lane == 0) {
#pragma unroll
        for (int i = 0; i < NACC; ++i) sred[wave][i] = v[i];
    }
    __syncthreads();
    if (threadIdx.x < NACC) {
        const float s = sred[0][threadIdx.x] + sred[1][threadIdx.x] +
                        sred[2][threadIdx.x] + sred[3][threadIdx.x];
        atomicAdd(&acc[b * 32 + threadIdx.x], s);
    }
}

__global__ void dba_solve(const float* __restrict__ acc,
                          const float* __restrict__ lmbda,
                          float* __restrict__ pose_out,
                          float* __restrict__ dp_ws, int B)
{
    const int b = blockIdx.x * blockDim.x + threadIdx.x;
    if (b >= B) return;
    float M[6][7];
    const float* a = acc + b * 32;
    int idx = 0;
#pragma unroll
    for (int i = 0; i < 6; ++i) {
#pragma unroll
        for (int j = i; j < 6; ++j) {
            const float t = a[idx++];
            M[i][j] = t;
            M[j][i] = t;
        }
    }
#pragma unroll
    for (int i = 0; i < 6; ++i) M[i][6] = a[21 + i];
    const float lam = lmbda[b];
#pragma unroll
    for (int i = 0; i < 6; ++i) M[i][i] += lam + 0.011f;

#pragma unroll
    for (int k = 0; k < 6; ++k) {
        const float piv = 1.0f / M[k][k];
#pragma unroll
        for (int j = 0; j < 7; ++j) M[k][j] *= piv;
#pragma unroll
        for (int i = 0; i < 6; ++i) {
            if (i == k) continue;
            const float f = M[i][k];
#pragma unroll
            for (int j = 0; j < 7; ++j) M[i][j] -= f * M[k][j];
        }
    }
#pragma unroll
    for (int i = 0; i < 6; ++i) {
        const float x = M[i][6];
        dp_ws[b * 6 + i] = x;                 // UNCLIPPED dp feeds pass 3
        pose_out[b * 6 + i] = fminf(fmaxf(x, -2.0f), 2.0f);
    }
}

// Slim pass 3: depth = gdinv - hii.dp from the 32B/pt cache (LLC-resident).
__global__ __launch_bounds__(256) void dba_depth_cached(
    const float* __restrict__ cache, const float* __restrict__ dp_ws,
    float* __restrict__ depth_out, int N)
{
    const int b = blockIdx.y;
    float dp[6];
#pragma unroll
    for (int i = 0; i < 6; ++i) dp[i] = dp_ws[b * 6 + i];

    const size_t basePt = (size_t)b * (size_t)N;
    const int P = N >> 1;
    const f4* __restrict__ cb = (const f4*)cache + basePt * 2;
    f2* __restrict__ out2 = (f2*)depth_out + (basePt >> 1);

    for (int pr = blockIdx.x * blockDim.x + threadIdx.x; pr < P;
         pr += gridDim.x * blockDim.x) {
        const f4 c0 = cb[(size_t)pr * 4 + 0];
        const f4 c1 = cb[(size_t)pr * 4 + 1];
        const f4 c2 = cb[(size_t)pr * 4 + 2];
        const f4 c3 = cb[(size_t)pr * 4 + 3];
        f2 o;
        o[0] = c1[2] - (c0[0] * dp[0] + c0[1] * dp[1] + c0[2] * dp[2] +
                        c0[3] * dp[3] + c1[0] * dp[4] + c1[1] * dp[5]);
        o[1] = c3[2] - (c2[0] * dp[0] + c2[1] * dp[1] + c2[2] * dp[2] +
                        c2[3] * dp[3] + c3[0] * dp[4] + c3[1] * dp[5]);
        out2[pr] = o;
    }
}

// Fallback pass 3 (full recompute from raw inputs) if workspace is too small.
__device__ __forceinline__ float depth_point(
    const float ja[6], const float jb[6], const float* __restrict__ dp,
    float r0, float r1, float conf, float nlam, float jd0, float jd1, float lam)
{
    float v = 0.f;
#pragma unroll
    for (int i = 0; i < 6; ++i)
        v += (ja[i] * jd0 + jb[i] * jd1) * dp[i];
    v *= conf;
    const float hdd = conf * (jd0 * jd0 + jd1 * jd1);
    const float inv = 1.0f / fmaxf(hdd + lam + nlam, 1e-4f);
    const float gd  = conf * (jd0 * r0 + jd1 * r1);
    return inv * (gd - v);
}

__global__ __launch_bounds__(256) void dba_depth_full(
    const float* __restrict__ r, const float* __restrict__ w,
    const float* __restrict__ J_p, const float* __restrict__ J_d,
    const float* __restrict__ lmbda, const float* __restrict__ dp_ws,
    float* __restrict__ depth_out, int N)
{
    const int b = blockIdx.y;
    const float lam = lmbda[b];
    float dp[6];
#pragma unroll
    for (int i = 0; i < 6; ++i) dp[i] = dp_ws[b * 6 + i];

    const size_t basePt = (size_t)b * (size_t)N;
    const int P = N >> 1;
    for (int pr = blockIdx.x * blockDim.x + threadIdx.x; pr < P;
         pr += gridDim.x * blockDim.x) {
        const size_t pt = basePt + ((size_t)pr << 1);
        const float4 rv = *(const float4*)(r + pt * 2);
        const float4 wv = *(const float4*)(w + pt * 2);
        const float4 jd = *(const float4*)(J_d + pt * 2);
        const float4* jp = (const float4*)(J_p + pt * 12);
        const float4 q0 = jp[0], q1 = jp[1], q2 = jp[2];
        const float4 q3 = jp[3], q4 = jp[4], q5 = jp[5];
        float2 outv;
        {
            const float ja[6] = {q0.x, q0.y, q0.z, q0.w, q1.x, q1.y};
            const float jb[6] = {q1.z, q1.w, q2.x, q2.y, q2.z, q2.w};
            outv.x = depth_point(ja, jb, dp, rv.x, rv.y, wv.x, wv.y, jd.x, jd.y, lam);
        }
        {
            const float ja[6] = {q3.x, q3.y, q3.z, q3.w, q4.x, q4.y};
            const float jb[6] = {q4.z, q4.w, q5.x, q5.y, q5.z, q5.w};
            outv.y = depth_point(ja, jb, dp, rv.z, rv.w, wv.z, wv.w, jd.z, jd.w, lam);
        }
        *(float2*)(depth_out + pt) = outv;
    }
}

extern "C" void kernel_launch(void* const* d_in, const int* in_sizes, int n_in,
                              void* d_out, int out_size, void* d_ws, size_t ws_size,
                              hipStream_t stream)
{
    const float* r   = (const float*)d_in[0];
    const float* w   = (const float*)d_in[1];
    const float* J_p = (const float*)d_in[2];
    const float* J_d = (const float*)d_in[3];
    const float* lmb = (const float*)d_in[4];
    const int B = in_sizes[4];            // 16
    const int N = in_sizes[0] / (B * 2);  // 196608

    // workspace layout (floats): acc[B*32] @0, dp[B*6] @512, cache @1024
    float* acc   = (float*)d_ws;
    float* dp_ws = (float*)d_ws + 512;
    float* cache = (float*)d_ws + 1024;
    float* out   = (float*)d_out;

    const size_t cacheBytes = (size_t)B * (size_t)N * 32;  // 8 floats/point
    const int use_cache = (ws_size >= 4096 + cacheBytes) ? 1 : 0;

    hipMemsetAsync(acc, 0, B * 32 * sizeof(float), stream);

    dim3 grid(96, B);
    dba_reduce<<<grid, 256, 0, stream>>>(r, w, J_p, J_d, lmb, acc,
                                         cache, use_cache, N);
    dba_solve<<<1, 64, 0, stream>>>(acc, lmb, out, dp_ws, B);
    if (use_cache) {
        dim3 dgrid(192, B);
        dba_depth_cached<<<dgrid, 256, 0, stream>>>(cache, dp_ws,
                                                    out + B * 6, N);
    } else {
        dim3 dgrid(192, B);
        dba_depth_full<<<dgrid, 256, 0, stream>>>(r, w, J_p, J_d, lmb, dp_ws,
                                                  out + B * 6, N);
    }
}